// Round 10
// baseline (362.168 us; speedup 1.0000x reference)
//
#include <hip/hip_runtime.h>

typedef __bf16 bf16x8 __attribute__((ext_vector_type(8)));
typedef float f32x4 __attribute__((ext_vector_type(4)));
typedef short short8 __attribute__((ext_vector_type(8)));

#define MFMA16(a, b, c) __builtin_amdgcn_mfma_f32_16x16x32_bf16(a, b, c, 0, 0, 0)

__device__ inline unsigned short bf16_rne(float x) {
  unsigned u = __builtin_bit_cast(unsigned, x);
  return (unsigned short)((u + 0x7FFFu + ((u >> 16) & 1u)) >> 16);
}
__device__ inline float bf16_tof(unsigned short s) {
  unsigned u = ((unsigned)s) << 16;
  return __builtin_bit_cast(float, u);
}
__device__ inline void split2(float x, unsigned short* hi, unsigned short* lo) {
  unsigned short h = bf16_rne(x);
  *hi = h;
  *lo = bf16_rne(x - bf16_tof(h));
}
__device__ inline float fast_rcp(float x) { return __builtin_amdgcn_rcpf(x); }

// ---------------- fp32 -> (hi, lo) bf16 split ----------------

__global__ __launch_bounds__(256) void conv_split_kernel(
    const float* __restrict__ x, unsigned short* __restrict__ xhi,
    unsigned short* __restrict__ xlo, int total4) {
  int i = blockIdx.x * 256 + threadIdx.x;
  if (i < total4) {
    float4 v = ((const float4*)x)[i];
    ushort4 h, l;
    split2(v.x, &h.x, &l.x);
    split2(v.y, &h.y, &l.y);
    split2(v.z, &h.z, &l.z);
    split2(v.w, &h.w, &l.w);
    ((ushort4*)xhi)[i] = h;
    ((ushort4*)xlo)[i] = l;
  }
}

// ---------------- weight frag prep ----------------

__global__ __launch_bounds__(256) void wprep_kernel(
    const float* __restrict__ W, const float* __restrict__ w_ih,
    const float* __restrict__ w_hh, unsigned short* __restrict__ frags) {
  int idx = blockIdx.x * 256 + threadIdx.x;
  if (idx >= 3 * 12 * 2 * 64) return;
  int lane = idx & 63;
  int ks = (idx >> 6) & 1;
  int tci = (idx >> 7) % 12;
  int set = idx / (12 * 2 * 64);
  int c = tci * 16 + (lane & 15);
  unsigned short* hi = frags + (size_t)set * 2 * 12288;
  unsigned short* lo = hi + 12288;
  size_t dbase = ((size_t)(tci * 2 + ks) * 64 + lane) * 8;
#pragma unroll
  for (int j = 0; j < 8; ++j) {
    int k = ks * 32 + ((lane >> 4) << 3) + j;
    float v;
    if (set == 0) v = W[((c >> 6) << 12) + (k << 6) + (c & 63)];
    else if (set == 1) v = w_ih[(c << 6) + k];
    else v = w_hh[(c << 6) + k];
    unsigned short h, l;
    split2(v, &h, &l);
    hi[dbase + j] = h;
    lo[dbase + j] = l;
  }
}

// ---------------- CSR build ----------------

__global__ __launch_bounds__(256) void count_kernel(
    const int* __restrict__ dst, unsigned* __restrict__ counts, int E) {
  int base = (blockIdx.x * 256 + threadIdx.x) * 4;
  if (base + 4 <= E) {
    int4 d = *(const int4*)(dst + base);
    atomicAdd(&counts[d.x], 1u);
    atomicAdd(&counts[d.y], 1u);
    atomicAdd(&counts[d.z], 1u);
    atomicAdd(&counts[d.w], 1u);
  } else {
    for (int k = base; k < E; ++k) atomicAdd(&counts[dst[k]], 1u);
  }
}

__global__ __launch_bounds__(1024) void scan_k1(
    const unsigned* __restrict__ counts, unsigned* __restrict__ offs,
    unsigned* __restrict__ bsums, int N) {
  __shared__ unsigned sm[1024];
  int tid = threadIdx.x;
  int i = blockIdx.x * 1024 + tid;
  unsigned v = (i < N) ? counts[i] : 0u;
  sm[tid] = v;
  __syncthreads();
  for (int ofs = 1; ofs < 1024; ofs <<= 1) {
    unsigned add = (tid >= ofs) ? sm[tid - ofs] : 0u;
    __syncthreads();
    sm[tid] += add;
    __syncthreads();
  }
  if (i < N) offs[i] = sm[tid] - v;
  if (tid == 0) bsums[blockIdx.x] = sm[1023];
}

__global__ __launch_bounds__(128) void scan_k2(
    unsigned* __restrict__ bsums, unsigned* __restrict__ offs, int M, int N) {
  __shared__ unsigned sm[128];
  int tid = threadIdx.x;
  unsigned v = (tid < M) ? bsums[tid] : 0u;
  sm[tid] = v;
  __syncthreads();
  for (int ofs = 1; ofs < 128; ofs <<= 1) {
    unsigned add = (tid >= ofs) ? sm[tid - ofs] : 0u;
    __syncthreads();
    sm[tid] += add;
    __syncthreads();
  }
  if (tid < M) bsums[tid] = sm[tid] - v;
  if (tid == 127) offs[N] = sm[127];
}

__global__ __launch_bounds__(256) void scan_k3(
    unsigned* __restrict__ offs, const unsigned* __restrict__ bsums, int N) {
  int i = blockIdx.x * 256 + threadIdx.x;
  if (i < N) offs[i] = offs[i] + bsums[i >> 10];
}

__global__ __launch_bounds__(128) void bin_init_kernel(
    const unsigned* __restrict__ offs, unsigned* __restrict__ bincur, int nbins) {
  int b = threadIdx.x;
  if (b < nbins) bincur[b] = offs[b << 10];
}

// pass 1: block-aggregated scatter into dst-bins.
#define SCHUNK 2048
__global__ __launch_bounds__(256) void bin_scatter_kernel(
    const int* __restrict__ src, const int* __restrict__ dst,
    const int* __restrict__ rel, const float* __restrict__ norm,
    unsigned* __restrict__ bincur, uint2* __restrict__ binbuf, int E) {
  __shared__ unsigned cnt[128];
  __shared__ unsigned base[128];
  int tid = threadIdx.x;
  int start = blockIdx.x * SCHUNK;
  if (tid < 128) cnt[tid] = 0u;
  __syncthreads();
  unsigned mybin[8];
  uint2 myrec[8];
#pragma unroll
  for (int i = 0; i < 8; ++i) {
    int e = start + i * 256 + tid;
    if (e < E) {
      int d = dst[e];
      mybin[i] = (unsigned)d >> 10;
      myrec[i].x = (unsigned)src[e] | ((unsigned)rel[e] << 17) |
                   ((unsigned)(d & 1023) << 19);
      myrec[i].y = __builtin_bit_cast(unsigned, norm[e]);
      atomicAdd(&cnt[mybin[i]], 1u);
    } else {
      mybin[i] = 0xFFFFFFFFu;
    }
  }
  __syncthreads();
  if (tid < 128) {
    unsigned c = cnt[tid];
    base[tid] = c ? atomicAdd(&bincur[tid], c) : 0u;
    cnt[tid] = 0u;
  }
  __syncthreads();
#pragma unroll
  for (int i = 0; i < 8; ++i) {
    if (mybin[i] != 0xFFFFFFFFu) {
      unsigned r = atomicAdd(&cnt[mybin[i]], 1u);
      binbuf[base[mybin[i]] + r] = myrec[i];
    }
  }
}

// pass 2: per-bin counting sort into final CSR positions (writes L2-resident)
__global__ __launch_bounds__(1024) void bin_sort_kernel(
    const uint2* __restrict__ binbuf, const unsigned* __restrict__ offs,
    uint2* __restrict__ epack, int N) {
  __shared__ unsigned cnt[1024];
  __shared__ unsigned offl[1024];
  int bin = blockIdx.x;
  int base = bin << 10;
  int tid = threadIdx.x;
  int hi = base + 1024;
  if (hi > N) hi = N;
  if (base + tid < N) offl[tid] = offs[base + tid];
  cnt[tid] = 0u;
  __syncthreads();
  unsigned start = offs[base];
  unsigned end = offs[hi];
  for (unsigned j = start + tid; j < end; j += 1024) {
    uint2 rec = binbuf[j];
    unsigned dlo = rec.x >> 19;
    unsigned r = atomicAdd(&cnt[dlo], 1u);
    epack[offl[dlo] + r] = rec;
  }
}

// ---------------- transform (MFMA): t[r][n][e] = sum_d x[n][d] W[r][d][e] ----------------

__global__ __launch_bounds__(256) void transform_kernel(
    const unsigned short* __restrict__ xhi, const unsigned short* __restrict__ xlo,
    const unsigned short* __restrict__ wfrag, float* __restrict__ t, int N, int NT) {
  int lane = threadIdx.x & 63;
  int w = threadIdx.x >> 6;
  bf16x8 bh[3][2], bl[3][2];
  const short8* fh = (const short8*)wfrag;
  const short8* fl = (const short8*)(wfrag + 12288);
#pragma unroll
  for (int ct = 0; ct < 3; ++ct)
#pragma unroll
    for (int ks = 0; ks < 2; ++ks) {
      int tci = w * 3 + ct;
      bh[ct][ks] = __builtin_bit_cast(bf16x8, fh[(tci * 2 + ks) * 64 + lane]);
      bl[ct][ks] = __builtin_bit_cast(bf16x8, fl[(tci * 2 + ks) * 64 + lane]);
    }
  int r15 = lane & 15, kq = lane >> 4;
  for (int nt = blockIdx.x; nt < NT; nt += gridDim.x) {
    int n0 = nt * 16;
    int row = n0 + r15;
    if (row >= N) row = N - 1;
    const short8* ah = (const short8*)(xhi + (((size_t)row) << 6) + (kq << 3));
    const short8* al = (const short8*)(xlo + (((size_t)row) << 6) + (kq << 3));
    bf16x8 axh[2], axl[2];
    axh[0] = __builtin_bit_cast(bf16x8, ah[0]);
    axh[1] = __builtin_bit_cast(bf16x8, ah[4]);
    axl[0] = __builtin_bit_cast(bf16x8, al[0]);
    axl[1] = __builtin_bit_cast(bf16x8, al[4]);
#pragma unroll
    for (int ct = 0; ct < 3; ++ct) {
      f32x4 acc = {0.f, 0.f, 0.f, 0.f};
#pragma unroll
      for (int ks = 0; ks < 2; ++ks) {
        acc = MFMA16(axh[ks], bh[ct][ks], acc);
        acc = MFMA16(axh[ks], bl[ct][ks], acc);
        acc = MFMA16(axl[ks], bh[ct][ks], acc);
      }
      int c = (w * 3 + ct) * 16 + r15;
      int rrel = c >> 6, e = c & 63;
      float* tb = t + (((size_t)rrel * N) << 6) + e;
#pragma unroll
      for (int reg = 0; reg < 4; ++reg) {
        int n = n0 + (kq << 2) + reg;
        if (n < N) tb[((size_t)n) << 6] = acc[reg];
      }
    }
  }
}

// ---------------- gather: 4 edges in flight per wave (16-lane groups) ----------------

__global__ __launch_bounds__(256) void gather_kernel(
    const float* __restrict__ t, const unsigned* __restrict__ offs,
    const uint2* __restrict__ epack,
    unsigned short* __restrict__ swhhi, unsigned short* __restrict__ swhlo, int N) {
  int tid = threadIdx.x;
  int lane = tid & 63;
  int n = __builtin_amdgcn_readfirstlane(blockIdx.x * 4 + (tid >> 6));
  if (n >= N) return;
  unsigned a = offs[n], b = offs[n + 1];
  int g = lane >> 4;          // edge group 0..3
  int cl = (lane & 15) << 2;  // channel base
  float acc0 = 0.f, acc1 = 0.f, acc2 = 0.f, acc3 = 0.f;
  for (unsigned j = a + g; j < b; j += 4) {
    uint2 e = epack[j];
    const float* row =
        t + (((size_t)((e.x >> 17) & 3) * N + (e.x & 0x1FFFFu)) << 6) + cl;
    float4 v = *(const float4*)row;
    float nv = __builtin_bit_cast(float, e.y);
    acc0 = fmaf(v.x, nv, acc0);
    acc1 = fmaf(v.y, nv, acc1);
    acc2 = fmaf(v.z, nv, acc2);
    acc3 = fmaf(v.w, nv, acc3);
  }
  acc0 += __shfl_xor(acc0, 16);
  acc1 += __shfl_xor(acc1, 16);
  acc2 += __shfl_xor(acc2, 16);
  acc3 += __shfl_xor(acc3, 16);
  acc0 += __shfl_xor(acc0, 32);
  acc1 += __shfl_xor(acc1, 32);
  acc2 += __shfl_xor(acc2, 32);
  acc3 += __shfl_xor(acc3, 32);
  if (g == 0) {
    ushort4 h, l;
    split2(acc0, &h.x, &l.x);
    split2(acc1, &h.y, &l.y);
    split2(acc2, &h.z, &l.z);
    split2(acc3, &h.w, &l.w);
    *(ushort4*)(swhhi + (((size_t)n) << 6) + cl) = h;
    *(ushort4*)(swhlo + (((size_t)n) << 6) + cl) = l;
  }
}

// ---------------- fused GRU: one 16-node tile per block, register gates ----------------
// Wave w owns 16-col slice c = w*16 + (lane&15) for gates r,z,n (tci = g*4+w).
// Short weight-fragment liveness keeps VGPR ~48 -> high occupancy (R8 lesson:
// occupancy beats load-elimination for this latency-bound kernel).
// LAYER=0: hstate=0, writes split h1 only. LAYER=1: h from split pair
// (hp = tof(hi)+tof(lo)), writes fp32 out.

template <int LAYER>
__global__ __launch_bounds__(256) void gru_kernel(
    const unsigned short* __restrict__ shi, const unsigned short* __restrict__ slo,
    const unsigned short* __restrict__ hhi, const unsigned short* __restrict__ hlo,
    const unsigned short* __restrict__ wfi, const unsigned short* __restrict__ wfh,
    const float* __restrict__ b_ih, const float* __restrict__ b_hh,
    float* __restrict__ outf, unsigned short* __restrict__ houthi,
    unsigned short* __restrict__ houtlo, int N) {
  int lane = threadIdx.x & 63;
  int w = threadIdx.x >> 6;
  int r15 = lane & 15, kq = lane >> 4;
  int c = (w << 4) + r15;

  const short8* fih = (const short8*)wfi;
  const short8* fil = (const short8*)(wfi + 12288);
  const short8* fhh = (const short8*)wfh;
  const short8* fhl = (const short8*)(wfh + 12288);
  bf16x8 bih[3][2], bil[3][2], bhh[3][2], bhl[3][2];
#pragma unroll
  for (int g = 0; g < 3; ++g)
#pragma unroll
    for (int ks = 0; ks < 2; ++ks) {
      int tci = (g << 2) + w;
      bih[g][ks] = __builtin_bit_cast(bf16x8, fih[(tci * 2 + ks) * 64 + lane]);
      bil[g][ks] = __builtin_bit_cast(bf16x8, fil[(tci * 2 + ks) * 64 + lane]);
      if (LAYER) {
        bhh[g][ks] = __builtin_bit_cast(bf16x8, fhh[(tci * 2 + ks) * 64 + lane]);
        bhl[g][ks] = __builtin_bit_cast(bf16x8, fhl[(tci * 2 + ks) * 64 + lane]);
      }
    }
  float bi[3], bh[3];
#pragma unroll
  for (int g = 0; g < 3; ++g) {
    bi[g] = b_ih[(g << 6) + c];
    bh[g] = b_hh[(g << 6) + c];
  }

  int n0 = blockIdx.x << 4;
  int row = n0 + r15;
  if (row >= N) row = N - 1;

  bf16x8 axh[2], axl[2], ahh2[2], ahl2[2];
  {
    const short8* ax0 = (const short8*)(shi + (((size_t)row) << 6) + (kq << 3));
    const short8* ax1 = (const short8*)(slo + (((size_t)row) << 6) + (kq << 3));
    axh[0] = __builtin_bit_cast(bf16x8, ax0[0]);
    axh[1] = __builtin_bit_cast(bf16x8, ax0[4]);
    axl[0] = __builtin_bit_cast(bf16x8, ax1[0]);
    axl[1] = __builtin_bit_cast(bf16x8, ax1[4]);
    if (LAYER) {
      const short8* ah0 = (const short8*)(hhi + (((size_t)row) << 6) + (kq << 3));
      const short8* ah1 = (const short8*)(hlo + (((size_t)row) << 6) + (kq << 3));
      ahh2[0] = __builtin_bit_cast(bf16x8, ah0[0]);
      ahh2[1] = __builtin_bit_cast(bf16x8, ah0[4]);
      ahl2[0] = __builtin_bit_cast(bf16x8, ah1[0]);
      ahl2[1] = __builtin_bit_cast(bf16x8, ah1[4]);
    }
  }

  f32x4 accx[3], acch[3];
#pragma unroll
  for (int g = 0; g < 3; ++g) {
    accx[g] = (f32x4){0.f, 0.f, 0.f, 0.f};
    acch[g] = (f32x4){0.f, 0.f, 0.f, 0.f};
#pragma unroll
    for (int ks = 0; ks < 2; ++ks) {
      accx[g] = MFMA16(axh[ks], bih[g][ks], accx[g]);
      accx[g] = MFMA16(axh[ks], bil[g][ks], accx[g]);
      accx[g] = MFMA16(axl[ks], bih[g][ks], accx[g]);
      if (LAYER) {
        acch[g] = MFMA16(ahh2[ks], bhh[g][ks], acch[g]);
        acch[g] = MFMA16(ahh2[ks], bhl[g][ks], acch[g]);
        acch[g] = MFMA16(ahl2[ks], bhh[g][ks], acch[g]);
      }
    }
  }

#pragma unroll
  for (int reg = 0; reg < 4; ++reg) {
    int n = n0 + (kq << 2) + reg;
    if (n >= N) break;
    size_t idx = (((size_t)n) << 6) + c;
    float hp = 0.f;
    if (LAYER) hp = bf16_tof(hhi[idx]) + bf16_tof(hlo[idx]);
    float gir = accx[0][reg] + bi[0];
    float giz = accx[1][reg] + bi[1];
    float gin = accx[2][reg] + bi[2];
    float ghr = (LAYER ? acch[0][reg] : 0.f) + bh[0];
    float ghz = (LAYER ? acch[1][reg] : 0.f) + bh[1];
    float ghn = (LAYER ? acch[2][reg] : 0.f) + bh[2];
    float r = fast_rcp(1.f + __expf(-(gir + ghr)));
    float z = fast_rcp(1.f + __expf(-(giz + ghz)));
    float nn = 1.f - 2.f * fast_rcp(1.f + __expf(2.f * (gin + r * ghn)));
    float o = (1.f - z) * nn + z * hp;
    if (LAYER) {
      outf[idx] = o;
    } else {
      unsigned short oh, ol;
      split2(o, &oh, &ol);
      houthi[idx] = oh;
      houtlo[idx] = ol;
    }
  }
}

// ---------------- batchnorm ----------------

__global__ __launch_bounds__(256) void bn_stats_kernel(
    const float* __restrict__ h, float* __restrict__ stats, int N) {
  int tid = threadIdx.x;
  int c = tid & 63;
  float s = 0.f, ss = 0.f;
  for (int n = blockIdx.x * 4 + (tid >> 6); n < N; n += gridDim.x * 4) {
    float v = h[(size_t)n * 64 + c];
    s += v;
    ss += v * v;
  }
  __shared__ float sm[2][256];
  sm[0][tid] = s;
  sm[1][tid] = ss;
  __syncthreads();
  if (tid < 64) {
    s = sm[0][tid] + sm[0][tid + 64] + sm[0][tid + 128] + sm[0][tid + 192];
    ss = sm[1][tid] + sm[1][tid + 64] + sm[1][tid + 128] + sm[1][tid + 192];
    atomicAdd(&stats[tid], s);
    atomicAdd(&stats[64 + tid], ss);
  }
}

__global__ __launch_bounds__(256) void bn_apply_kernel(
    float* out, const float* __restrict__ stats,
    const float* __restrict__ gamma, const float* __restrict__ beta,
    int N, int total) {
  int idx = blockIdx.x * 256 + threadIdx.x;
  if (idx >= total) return;
  int c = idx & 63;
  float invN = 1.f / (float)N;
  float mean = stats[c] * invN;
  float var = stats[64 + c] * invN - mean * mean;
  float sc = rsqrtf(var + 1e-5f) * gamma[c];
  float sh = beta[c] - mean * sc;
  out[idx] = out[idx] * sc + sh;
}

// ---------------- launch ----------------

extern "C" void kernel_launch(void* const* d_in, const int* in_sizes, int n_in,
                              void* d_out, int out_size, void* d_ws, size_t ws_size,
                              hipStream_t stream) {
  const float* h     = (const float*)d_in[0];
  const float* norm  = (const float*)d_in[1];
  const float* W     = (const float*)d_in[2];
  const float* w_ih  = (const float*)d_in[3];
  const float* w_hh  = (const float*)d_in[4];
  const float* b_ih  = (const float*)d_in[5];
  const float* b_hh  = (const float*)d_in[6];
  const float* gamma = (const float*)d_in[7];
  const float* beta  = (const float*)d_in[8];
  const int* src     = (const int*)d_in[9];
  const int* dst     = (const int*)d_in[10];
  const int* rel     = (const int*)d_in[11];
  float* out = (float*)d_out;

  const int N = in_sizes[0] / 64;
  const int E = in_sizes[1];
  const int NT = (N + 15) / 16;
  const int NBINS = (N + 1023) / 1024;

  char* wsp = (char*)d_ws;
  float* t = (float*)wsp;              wsp += (size_t)3 * N * 64 * 4;
  unsigned short* xhi = (unsigned short*)wsp; wsp += (size_t)N * 64 * 2;
  unsigned short* xlo = (unsigned short*)wsp; wsp += (size_t)N * 64 * 2;
  unsigned short* swhhi = (unsigned short*)wsp; wsp += (size_t)N * 64 * 2;
  unsigned short* swhlo = (unsigned short*)wsp; wsp += (size_t)N * 64 * 2;
  unsigned short* frags = (unsigned short*)wsp; wsp += 6 * 12288 * 2;
  unsigned* offs = (unsigned*)wsp;   wsp += ((size_t)N + 4) * 4;
  unsigned* cursor = (unsigned*)wsp; wsp += (size_t)N * 4;
  uint2* epack = (uint2*)wsp;        wsp += (size_t)E * 8;
  unsigned* bsums = (unsigned*)wsp;  wsp += 128 * 4;
  float* stats = (float*)wsp;        wsp += 128 * 4;

  uint2* binbuf = (uint2*)t;  // aliases t: dead until transform
  unsigned* bincur = cursor;  // reuse per-dst counter buffer (dead after scan)

  const unsigned short* frag_t = frags;
  const unsigned short* frag_i = frags + 2 * 12288;
  const unsigned short* frag_h = frags + 4 * 12288;

  const int M = (N + 1023) / 1024;

  hipMemsetAsync(cursor, 0, (size_t)N * 4, stream);
  hipMemsetAsync(stats, 0, 128 * 4, stream);

  wprep_kernel<<<18, 256, 0, stream>>>(W, w_ih, w_hh, frags);
  conv_split_kernel<<<(N * 16 + 255) / 256, 256, 0, stream>>>(h, xhi, xlo, N * 16);

  // CSR over dst (graph is layer-invariant): count -> scan -> binned sort
  count_kernel<<<(E / 4 + 255) / 256, 256, 0, stream>>>(dst, cursor, E);
  scan_k1<<<M, 1024, 0, stream>>>(cursor, offs, bsums, N);
  scan_k2<<<1, 128, 0, stream>>>(bsums, offs, M, N);
  scan_k3<<<(N + 255) / 256, 256, 0, stream>>>(offs, bsums, N);
  bin_init_kernel<<<1, 128, 0, stream>>>(offs, bincur, NBINS);
  bin_scatter_kernel<<<(E + SCHUNK - 1) / SCHUNK, 256, 0, stream>>>(
      src, dst, rel, norm, bincur, binbuf, E);
  bin_sort_kernel<<<NBINS, 1024, 0, stream>>>(binbuf, offs, epack, N);

  // layer 0 (hstate = 0): writes h1 split only -> xhi/xlo
  transform_kernel<<<1024, 256, 0, stream>>>(xhi, xlo, frag_t, t, N, NT);
  gather_kernel<<<(N + 3) / 4, 256, 0, stream>>>(t, offs, epack, swhhi, swhlo, N);
  gru_kernel<0><<<NT, 256, 0, stream>>>(swhhi, swhlo, nullptr, nullptr,
                                        frag_i, frag_h, b_ih, b_hh,
                                        nullptr, xhi, xlo, N);

  // layer 1: h from split (hp reconstructed); writes fp32 out
  transform_kernel<<<1024, 256, 0, stream>>>(xhi, xlo, frag_t, t, N, NT);
  gather_kernel<<<(N + 3) / 4, 256, 0, stream>>>(t, offs, epack, swhhi, swhlo, N);
  gru_kernel<1><<<NT, 256, 0, stream>>>(swhhi, swhlo, xhi, xlo,
                                        frag_i, frag_h, b_ih, b_hh,
                                        out, nullptr, nullptr, N);

  bn_stats_kernel<<<256, 256, 0, stream>>>(out, stats, N);
  int total = N * 64;
  bn_apply_kernel<<<(total + 255) / 256, 256, 0, stream>>>(out, stats, gamma,
                                                           beta, N, total);
}

// Round 11
// 324.877 us; speedup vs baseline: 1.1148x; 1.1148x over previous
//
#include <hip/hip_runtime.h>

typedef __bf16 bf16x8 __attribute__((ext_vector_type(8)));
typedef float f32x4 __attribute__((ext_vector_type(4)));
typedef short short8 __attribute__((ext_vector_type(8)));

#define MFMA16(a, b, c) __builtin_amdgcn_mfma_f32_16x16x32_bf16(a, b, c, 0, 0, 0)

__device__ inline unsigned short bf16_rne(float x) {
  unsigned u = __builtin_bit_cast(unsigned, x);
  return (unsigned short)((u + 0x7FFFu + ((u >> 16) & 1u)) >> 16);
}
__device__ inline float bf16_tof(unsigned short s) {
  unsigned u = ((unsigned)s) << 16;
  return __builtin_bit_cast(float, u);
}
__device__ inline void split2(float x, unsigned short* hi, unsigned short* lo) {
  unsigned short h = bf16_rne(x);
  *hi = h;
  *lo = bf16_rne(x - bf16_tof(h));
}
__device__ inline float fast_rcp(float x) { return __builtin_amdgcn_rcpf(x); }

// ---------------- weight frag prep ----------------
// set0 (Wcat for gatherw): B[k=r*64+d][c=e], K=192, 4 col-tiles x 6 k-chunks.
//   layout: ((tci*6+ks)*64+lane)*8+j, hi at frags[0], lo at frags[12288].
// set1/set2 (w_ih/w_hh for gru): B[k=d][c], 12 col-tiles x 2 k-chunks, as before.

__global__ __launch_bounds__(256) void wprep_kernel(
    const float* __restrict__ W, const float* __restrict__ w_ih,
    const float* __restrict__ w_hh, unsigned short* __restrict__ frags) {
  int idx = blockIdx.x * 256 + threadIdx.x;
  if (idx < 1536) {
    int lane = idx & 63;
    int ks = (idx >> 6) % 6;
    int tci = idx / (6 * 64);
    int c = tci * 16 + (lane & 15);
    size_t dbase = ((size_t)(tci * 6 + ks) * 64 + lane) * 8;
#pragma unroll
    for (int j = 0; j < 8; ++j) {
      int k = ks * 32 + ((lane >> 4) << 3) + j;  // 0..191
      int r = k >> 6, d = k & 63;
      float v = W[(r << 12) + (d << 6) + c];
      unsigned short h, l;
      split2(v, &h, &l);
      frags[dbase + j] = h;
      frags[12288 + dbase + j] = l;
    }
  } else if (idx < 1536 + 2 * 1536) {
    int i2 = idx - 1536;
    int set = i2 / 1536;  // 0 -> w_ih, 1 -> w_hh
    int i3 = i2 % 1536;
    int lane = i3 & 63;
    int ks = (i3 >> 6) & 1;
    int tci = (i3 >> 7) % 12;
    int c = tci * 16 + (lane & 15);
    unsigned short* hi = frags + (size_t)(2 + 2 * set) * 12288;
    unsigned short* lo = hi + 12288;
    size_t dbase = ((size_t)(tci * 2 + ks) * 64 + lane) * 8;
    const float* wsrc = set ? w_hh : w_ih;
#pragma unroll
    for (int j = 0; j < 8; ++j) {
      int k = ks * 32 + ((lane >> 4) << 3) + j;
      float v = wsrc[(c << 6) + k];
      unsigned short h, l;
      split2(v, &h, &l);
      hi[dbase + j] = h;
      lo[dbase + j] = l;
    }
  }
}

// ---------------- CSR build ----------------

__global__ __launch_bounds__(256) void count_kernel(
    const int* __restrict__ dst, unsigned* __restrict__ counts, int E) {
  int base = (blockIdx.x * 256 + threadIdx.x) * 4;
  if (base + 4 <= E) {
    int4 d = *(const int4*)(dst + base);
    atomicAdd(&counts[d.x], 1u);
    atomicAdd(&counts[d.y], 1u);
    atomicAdd(&counts[d.z], 1u);
    atomicAdd(&counts[d.w], 1u);
  } else {
    for (int k = base; k < E; ++k) atomicAdd(&counts[dst[k]], 1u);
  }
}

__global__ __launch_bounds__(1024) void scan_k1(
    const unsigned* __restrict__ counts, unsigned* __restrict__ offs,
    unsigned* __restrict__ bsums, int N) {
  __shared__ unsigned sm[1024];
  int tid = threadIdx.x;
  int i = blockIdx.x * 1024 + tid;
  unsigned v = (i < N) ? counts[i] : 0u;
  sm[tid] = v;
  __syncthreads();
  for (int ofs = 1; ofs < 1024; ofs <<= 1) {
    unsigned add = (tid >= ofs) ? sm[tid - ofs] : 0u;
    __syncthreads();
    sm[tid] += add;
    __syncthreads();
  }
  if (i < N) offs[i] = sm[tid] - v;
  if (tid == 0) bsums[blockIdx.x] = sm[1023];
}

__global__ __launch_bounds__(128) void scan_k2(
    unsigned* __restrict__ bsums, unsigned* __restrict__ offs, int M, int N) {
  __shared__ unsigned sm[128];
  int tid = threadIdx.x;
  unsigned v = (tid < M) ? bsums[tid] : 0u;
  sm[tid] = v;
  __syncthreads();
  for (int ofs = 1; ofs < 128; ofs <<= 1) {
    unsigned add = (tid >= ofs) ? sm[tid - ofs] : 0u;
    __syncthreads();
    sm[tid] += add;
    __syncthreads();
  }
  if (tid < M) bsums[tid] = sm[tid] - v;
  if (tid == 127) offs[N] = sm[127];
}

__global__ __launch_bounds__(256) void scan_k3(
    unsigned* __restrict__ offs, const unsigned* __restrict__ bsums, int N) {
  int i = blockIdx.x * 256 + threadIdx.x;
  if (i < N) offs[i] = offs[i] + bsums[i >> 10];
}

__global__ __launch_bounds__(128) void bin_init_kernel(
    const unsigned* __restrict__ offs, unsigned* __restrict__ bincur, int nbins) {
  int b = threadIdx.x;
  if (b < nbins) bincur[b] = offs[b << 10];
}

// pass 1: block-aggregated scatter into dst-bins.
#define SCHUNK 2048
__global__ __launch_bounds__(256) void bin_scatter_kernel(
    const int* __restrict__ src, const int* __restrict__ dst,
    const int* __restrict__ rel, const float* __restrict__ norm,
    unsigned* __restrict__ bincur, uint2* __restrict__ binbuf, int E) {
  __shared__ unsigned cnt[128];
  __shared__ unsigned base[128];
  int tid = threadIdx.x;
  int start = blockIdx.x * SCHUNK;
  if (tid < 128) cnt[tid] = 0u;
  __syncthreads();
  unsigned mybin[8];
  uint2 myrec[8];
#pragma unroll
  for (int i = 0; i < 8; ++i) {
    int e = start + i * 256 + tid;
    if (e < E) {
      int d = dst[e];
      mybin[i] = (unsigned)d >> 10;
      myrec[i].x = (unsigned)src[e] | ((unsigned)rel[e] << 17) |
                   ((unsigned)(d & 1023) << 19);
      myrec[i].y = __builtin_bit_cast(unsigned, norm[e]);
      atomicAdd(&cnt[mybin[i]], 1u);
    } else {
      mybin[i] = 0xFFFFFFFFu;
    }
  }
  __syncthreads();
  if (tid < 128) {
    unsigned c = cnt[tid];
    base[tid] = c ? atomicAdd(&bincur[tid], c) : 0u;
    cnt[tid] = 0u;
  }
  __syncthreads();
#pragma unroll
  for (int i = 0; i < 8; ++i) {
    if (mybin[i] != 0xFFFFFFFFu) {
      unsigned r = atomicAdd(&cnt[mybin[i]], 1u);
      binbuf[base[mybin[i]] + r] = myrec[i];
    }
  }
}

// pass 2: per-bin counting sort into final CSR positions (writes L2-resident)
__global__ __launch_bounds__(1024) void bin_sort_kernel(
    const uint2* __restrict__ binbuf, const unsigned* __restrict__ offs,
    uint2* __restrict__ epack, int N) {
  __shared__ unsigned cnt[1024];
  __shared__ unsigned offl[1024];
  int bin = blockIdx.x;
  int base = bin << 10;
  int tid = threadIdx.x;
  int hi = base + 1024;
  if (hi > N) hi = N;
  if (base + tid < N) offl[tid] = offs[base + tid];
  cnt[tid] = 0u;
  __syncthreads();
  unsigned start = offs[base];
  unsigned end = offs[hi];
  for (unsigned j = start + tid; j < end; j += 1024) {
    uint2 rec = binbuf[j];
    unsigned dlo = rec.x >> 19;
    unsigned r = atomicAdd(&cnt[dlo], 1u);
    epack[offl[dlo] + r] = rec;
  }
}

// ---------------- fused gather + GEMM ----------------
// swh[n] = sum_r (sum_{e: dst=n, rel=r} norm_e * x[src_e]) @ W[r]
// Phase 1: 16 nodes/block, one 16-lane group per node, z[3][64] accumulated
//   in fp32 registers from fp32 x rows (25.6 MB working set, L3-resident).
// Phase 2: z -> LDS [16][192] -> K=192 split-bf16 MFMA with resident W frags.

__global__ __launch_bounds__(256) void gatherw_kernel(
    const float* __restrict__ xf, const unsigned* __restrict__ offs,
    const uint2* __restrict__ epack, const unsigned short* __restrict__ wfrag,
    unsigned short* __restrict__ swhhi, unsigned short* __restrict__ swhlo, int N) {
  __shared__ float zld[16][196];
  int tid = threadIdx.x;
  int g = tid >> 4, l16 = tid & 15;
  int n0 = blockIdx.x << 4;
  int n = n0 + g;
  int c4 = l16 << 2;

  float z[3][4] = {};
  if (n < N) {
    unsigned a = offs[n], b = offs[n + 1];
    unsigned j = a;
    for (; j + 2 <= b; j += 2) {
      uint2 e0 = epack[j];
      uint2 e1 = epack[j + 1];
      float4 v0 = *(const float4*)(xf + (((size_t)(e0.x & 0x1FFFFu)) << 6) + c4);
      float4 v1 = *(const float4*)(xf + (((size_t)(e1.x & 0x1FFFFu)) << 6) + c4);
      float nv0 = __builtin_bit_cast(float, e0.y);
      float nv1 = __builtin_bit_cast(float, e1.y);
      int r0 = (e0.x >> 17) & 3;
      int r1 = (e1.x >> 17) & 3;
#pragma unroll
      for (int rr = 0; rr < 3; ++rr) {
        float m0 = (r0 == rr) ? nv0 : 0.f;
        float m1 = (r1 == rr) ? nv1 : 0.f;
        z[rr][0] = fmaf(m0, v0.x, fmaf(m1, v1.x, z[rr][0]));
        z[rr][1] = fmaf(m0, v0.y, fmaf(m1, v1.y, z[rr][1]));
        z[rr][2] = fmaf(m0, v0.z, fmaf(m1, v1.z, z[rr][2]));
        z[rr][3] = fmaf(m0, v0.w, fmaf(m1, v1.w, z[rr][3]));
      }
    }
    if (j < b) {
      uint2 e0 = epack[j];
      float4 v0 = *(const float4*)(xf + (((size_t)(e0.x & 0x1FFFFu)) << 6) + c4);
      float nv0 = __builtin_bit_cast(float, e0.y);
      int r0 = (e0.x >> 17) & 3;
#pragma unroll
      for (int rr = 0; rr < 3; ++rr) {
        float m0 = (r0 == rr) ? nv0 : 0.f;
        z[rr][0] = fmaf(m0, v0.x, z[rr][0]);
        z[rr][1] = fmaf(m0, v0.y, z[rr][1]);
        z[rr][2] = fmaf(m0, v0.z, z[rr][2]);
        z[rr][3] = fmaf(m0, v0.w, z[rr][3]);
      }
    }
  }
#pragma unroll
  for (int rr = 0; rr < 3; ++rr)
#pragma unroll
    for (int i = 0; i < 4; ++i)
      zld[g][rr * 64 + c4 + i] = z[rr][i];
  __syncthreads();

  // MFMA phase: wave w -> output cols w*16..w*16+15, K=192 in 6 chunks
  int lane = tid & 63, w = tid >> 6;
  int r15 = lane & 15, kq = lane >> 4;
  const short8* fh = (const short8*)wfrag;
  const short8* fl = (const short8*)(wfrag + 12288);
  f32x4 acc = {0.f, 0.f, 0.f, 0.f};
#pragma unroll
  for (int ks = 0; ks < 6; ++ks) {
    const float* zr = &zld[r15][ks * 32 + (kq << 3)];
    short8 th, tl;
#pragma unroll
    for (int jj = 0; jj < 8; ++jj) {
      unsigned short h_, l_;
      split2(zr[jj], &h_, &l_);
      th[jj] = (short)h_;
      tl[jj] = (short)l_;
    }
    bf16x8 ahi = __builtin_bit_cast(bf16x8, th);
    bf16x8 alo = __builtin_bit_cast(bf16x8, tl);
    bf16x8 bhi = __builtin_bit_cast(bf16x8, fh[(w * 6 + ks) * 64 + lane]);
    bf16x8 blo = __builtin_bit_cast(bf16x8, fl[(w * 6 + ks) * 64 + lane]);
    acc = MFMA16(ahi, bhi, acc);
    acc = MFMA16(ahi, blo, acc);
    acc = MFMA16(alo, bhi, acc);
  }
  int c = (w << 4) + r15;
#pragma unroll
  for (int reg = 0; reg < 4; ++reg) {
    int nn = n0 + (kq << 2) + reg;
    if (nn < N) {
      unsigned short h_, l_;
      split2(acc[reg], &h_, &l_);
      swhhi[(((size_t)nn) << 6) + c] = h_;
      swhlo[(((size_t)nn) << 6) + c] = l_;
    }
  }
}

// ---------------- fused GRU: one 16-node tile per block, register gates ----------------
// LAYER=0: hstate=0; writes fp32 h1 (for next gather) + split h1 (for gru MFMA).
// LAYER=1: h from split pair (hp = tof(hi)+tof(lo)); writes fp32 out.

template <int LAYER>
__global__ __launch_bounds__(256) void gru_kernel(
    const unsigned short* __restrict__ shi, const unsigned short* __restrict__ slo,
    const unsigned short* __restrict__ hhi, const unsigned short* __restrict__ hlo,
    const unsigned short* __restrict__ wfi, const unsigned short* __restrict__ wfh,
    const float* __restrict__ b_ih, const float* __restrict__ b_hh,
    float* __restrict__ outf, unsigned short* __restrict__ houthi,
    unsigned short* __restrict__ houtlo, int N) {
  int lane = threadIdx.x & 63;
  int w = threadIdx.x >> 6;
  int r15 = lane & 15, kq = lane >> 4;
  int c = (w << 4) + r15;

  const short8* fih = (const short8*)wfi;
  const short8* fil = (const short8*)(wfi + 12288);
  const short8* fhh = (const short8*)wfh;
  const short8* fhl = (const short8*)(wfh + 12288);
  bf16x8 bih[3][2], bil[3][2], bhh[3][2], bhl[3][2];
#pragma unroll
  for (int g = 0; g < 3; ++g)
#pragma unroll
    for (int ks = 0; ks < 2; ++ks) {
      int tci = (g << 2) + w;
      bih[g][ks] = __builtin_bit_cast(bf16x8, fih[(tci * 2 + ks) * 64 + lane]);
      bil[g][ks] = __builtin_bit_cast(bf16x8, fil[(tci * 2 + ks) * 64 + lane]);
      if (LAYER) {
        bhh[g][ks] = __builtin_bit_cast(bf16x8, fhh[(tci * 2 + ks) * 64 + lane]);
        bhl[g][ks] = __builtin_bit_cast(bf16x8, fhl[(tci * 2 + ks) * 64 + lane]);
      }
    }
  float bi[3], bh[3];
#pragma unroll
  for (int g = 0; g < 3; ++g) {
    bi[g] = b_ih[(g << 6) + c];
    bh[g] = b_hh[(g << 6) + c];
  }

  int n0 = blockIdx.x << 4;
  int row = n0 + r15;
  if (row >= N) row = N - 1;

  bf16x8 axh[2], axl[2], ahh2[2], ahl2[2];
  {
    const short8* ax0 = (const short8*)(shi + (((size_t)row) << 6) + (kq << 3));
    const short8* ax1 = (const short8*)(slo + (((size_t)row) << 6) + (kq << 3));
    axh[0] = __builtin_bit_cast(bf16x8, ax0[0]);
    axh[1] = __builtin_bit_cast(bf16x8, ax0[4]);
    axl[0] = __builtin_bit_cast(bf16x8, ax1[0]);
    axl[1] = __builtin_bit_cast(bf16x8, ax1[4]);
    if (LAYER) {
      const short8* ah0 = (const short8*)(hhi + (((size_t)row) << 6) + (kq << 3));
      const short8* ah1 = (const short8*)(hlo + (((size_t)row) << 6) + (kq << 3));
      ahh2[0] = __builtin_bit_cast(bf16x8, ah0[0]);
      ahh2[1] = __builtin_bit_cast(bf16x8, ah0[4]);
      ahl2[0] = __builtin_bit_cast(bf16x8, ah1[0]);
      ahl2[1] = __builtin_bit_cast(bf16x8, ah1[4]);
    }
  }

  f32x4 accx[3], acch[3];
#pragma unroll
  for (int g = 0; g < 3; ++g) {
    accx[g] = (f32x4){0.f, 0.f, 0.f, 0.f};
    acch[g] = (f32x4){0.f, 0.f, 0.f, 0.f};
#pragma unroll
    for (int ks = 0; ks < 2; ++ks) {
      accx[g] = MFMA16(axh[ks], bih[g][ks], accx[g]);
      accx[g] = MFMA16(axh[ks], bil[g][ks], accx[g]);
      accx[g] = MFMA16(axl[ks], bih[g][ks], accx[g]);
      if (LAYER) {
        acch[g] = MFMA16(ahh2[ks], bhh[g][ks], acch[g]);
        acch[g] = MFMA16(ahh2[ks], bhl[g][ks], acch[g]);
        acch[g] = MFMA16(ahl2[ks], bhh[g][ks], acch[g]);
      }
    }
  }

#pragma unroll
  for (int reg = 0; reg < 4; ++reg) {
    int n = n0 + (kq << 2) + reg;
    if (n >= N) break;
    size_t idx = (((size_t)n) << 6) + c;
    float hp = 0.f;
    if (LAYER) hp = bf16_tof(hhi[idx]) + bf16_tof(hlo[idx]);
    float gir = accx[0][reg] + bi[0];
    float giz = accx[1][reg] + bi[1];
    float gin = accx[2][reg] + bi[2];
    float ghr = (LAYER ? acch[0][reg] : 0.f) + bh[0];
    float ghz = (LAYER ? acch[1][reg] : 0.f) + bh[1];
    float ghn = (LAYER ? acch[2][reg] : 0.f) + bh[2];
    float r = fast_rcp(1.f + __expf(-(gir + ghr)));
    float z = fast_rcp(1.f + __expf(-(giz + ghz)));
    float nn = 1.f - 2.f * fast_rcp(1.f + __expf(2.f * (gin + r * ghn)));
    float o = (1.f - z) * nn + z * hp;
    outf[idx] = o;
    if (!LAYER) {
      unsigned short oh, ol;
      split2(o, &oh, &ol);
      houthi[idx] = oh;
      houtlo[idx] = ol;
    }
  }
}

// ---------------- batchnorm ----------------

__global__ __launch_bounds__(256) void bn_stats_kernel(
    const float* __restrict__ h, float* __restrict__ stats, int N) {
  int tid = threadIdx.x;
  int c = tid & 63;
  float s = 0.f, ss = 0.f;
  for (int n = blockIdx.x * 4 + (tid >> 6); n < N; n += gridDim.x * 4) {
    float v = h[(size_t)n * 64 + c];
    s += v;
    ss += v * v;
  }
  __shared__ float sm[2][256];
  sm[0][tid] = s;
  sm[1][tid] = ss;
  __syncthreads();
  if (tid < 64) {
    s = sm[0][tid] + sm[0][tid + 64] + sm[0][tid + 128] + sm[0][tid + 192];
    ss = sm[1][tid] + sm[1][tid + 64] + sm[1][tid + 128] + sm[1][tid + 192];
    atomicAdd(&stats[tid], s);
    atomicAdd(&stats[64 + tid], ss);
  }
}

__global__ __launch_bounds__(256) void bn_apply_kernel(
    float* out, const float* __restrict__ stats,
    const float* __restrict__ gamma, const float* __restrict__ beta,
    int N, int total) {
  int idx = blockIdx.x * 256 + threadIdx.x;
  if (idx >= total) return;
  int c = idx & 63;
  float invN = 1.f / (float)N;
  float mean = stats[c] * invN;
  float var = stats[64 + c] * invN - mean * mean;
  float sc = rsqrtf(var + 1e-5f) * gamma[c];
  float sh = beta[c] - mean * sc;
  out[idx] = out[idx] * sc + sh;
}

// ---------------- launch ----------------

extern "C" void kernel_launch(void* const* d_in, const int* in_sizes, int n_in,
                              void* d_out, int out_size, void* d_ws, size_t ws_size,
                              hipStream_t stream) {
  const float* h     = (const float*)d_in[0];
  const float* norm  = (const float*)d_in[1];
  const float* W     = (const float*)d_in[2];
  const float* w_ih  = (const float*)d_in[3];
  const float* w_hh  = (const float*)d_in[4];
  const float* b_ih  = (const float*)d_in[5];
  const float* b_hh  = (const float*)d_in[6];
  const float* gamma = (const float*)d_in[7];
  const float* beta  = (const float*)d_in[8];
  const int* src     = (const int*)d_in[9];
  const int* dst     = (const int*)d_in[10];
  const int* rel     = (const int*)d_in[11];
  float* out = (float*)d_out;

  const int N = in_sizes[0] / 64;
  const int E = in_sizes[1];
  const int NT = (N + 15) / 16;
  const int NBINS = (N + 1023) / 1024;

  char* wsp = (char*)d_ws;
  float* hf = (float*)wsp;                      wsp += (size_t)N * 64 * 4;   // fp32 h1
  unsigned short* xhi = (unsigned short*)wsp;   wsp += (size_t)N * 64 * 2;   // h1 split hi
  unsigned short* xlo = (unsigned short*)wsp;   wsp += (size_t)N * 64 * 2;
  unsigned short* swhhi = (unsigned short*)wsp; wsp += (size_t)N * 64 * 2;
  unsigned short* swhlo = (unsigned short*)wsp; wsp += (size_t)N * 64 * 2;
  unsigned short* frags = (unsigned short*)wsp; wsp += 6 * 12288 * 2;
  unsigned* offs = (unsigned*)wsp;   wsp += ((size_t)N + 4) * 4;
  unsigned* cursor = (unsigned*)wsp; wsp += (size_t)N * 4;
  uint2* epack = (uint2*)wsp;        wsp += (size_t)E * 8;
  unsigned* bsums = (unsigned*)wsp;  wsp += 128 * 4;
  float* stats = (float*)wsp;        wsp += 128 * 4;

  uint2* binbuf = (uint2*)hf;  // aliases hf: dead until gru<0> writes it
  unsigned* bincur = cursor;   // reuse per-dst counter buffer (dead after scan)

  const unsigned short* frag_t = frags;
  const unsigned short* frag_i = frags + 2 * 12288;
  const unsigned short* frag_h = frags + 4 * 12288;

  const int M = (N + 1023) / 1024;

  hipMemsetAsync(cursor, 0, (size_t)N * 4, stream);
  hipMemsetAsync(stats, 0, 128 * 4, stream);

  wprep_kernel<<<18, 256, 0, stream>>>(W, w_ih, w_hh, frags);

  // CSR over dst (graph is layer-invariant): count -> scan -> binned sort
  count_kernel<<<(E / 4 + 255) / 256, 256, 0, stream>>>(dst, cursor, E);
  scan_k1<<<M, 1024, 0, stream>>>(cursor, offs, bsums, N);
  scan_k2<<<1, 128, 0, stream>>>(bsums, offs, M, N);
  scan_k3<<<(N + 255) / 256, 256, 0, stream>>>(offs, bsums, N);
  bin_init_kernel<<<1, 128, 0, stream>>>(offs, bincur, NBINS);
  bin_scatter_kernel<<<(E + SCHUNK - 1) / SCHUNK, 256, 0, stream>>>(
      src, dst, rel, norm, bincur, binbuf, E);
  bin_sort_kernel<<<NBINS, 1024, 0, stream>>>(binbuf, offs, epack, N);

  // layer 0: gather+GEMM from input h (fp32); gru writes fp32 h1 + split h1
  gatherw_kernel<<<NT, 256, 0, stream>>>(h, offs, epack, frag_t, swhhi, swhlo, N);
  gru_kernel<0><<<NT, 256, 0, stream>>>(swhhi, swhlo, nullptr, nullptr,
                                        frag_i, frag_h, b_ih, b_hh,
                                        hf, xhi, xlo, N);

  // layer 1: gather+GEMM from fp32 h1; gru h-path from split h1; writes out
  gatherw_kernel<<<NT, 256, 0, stream>>>(hf, offs, epack, frag_t, swhhi, swhlo, N);
  gru_kernel<1><<<NT, 256, 0, stream>>>(swhhi, swhlo, xhi, xlo,
                                        frag_i, frag_h, b_ih, b_hh,
                                        out, nullptr, nullptr, N);

  bn_stats_kernel<<<256, 256, 0, stream>>>(out, stats, N);
  int total = N * 64;
  bn_apply_kernel<<<(total + 255) / 256, 256, 0, stream>>>(out, stats, gamma,
                                                           beta, N, total);
}

// Round 12
// 307.766 us; speedup vs baseline: 1.1768x; 1.0556x over previous
//
#include <hip/hip_runtime.h>

typedef __bf16 bf16x8 __attribute__((ext_vector_type(8)));
typedef float f32x4 __attribute__((ext_vector_type(4)));
typedef short short8 __attribute__((ext_vector_type(8)));

#define MFMA16(a, b, c) __builtin_amdgcn_mfma_f32_16x16x32_bf16(a, b, c, 0, 0, 0)

__device__ inline unsigned short bf16_rne(float x) {
  unsigned u = __builtin_bit_cast(unsigned, x);
  return (unsigned short)((u + 0x7FFFu + ((u >> 16) & 1u)) >> 16);
}
__device__ inline float bf16_tof(unsigned short s) {
  unsigned u = ((unsigned)s) << 16;
  return __builtin_bit_cast(float, u);
}
__device__ inline void split2(float x, unsigned short* hi, unsigned short* lo) {
  unsigned short h = bf16_rne(x);
  *hi = h;
  *lo = bf16_rne(x - bf16_tof(h));
}
__device__ inline float fast_rcp(float x) { return __builtin_amdgcn_rcpf(x); }

// ---------------- weight frag prep ----------------
// set0 (Wcat, K=192): ((tci*6+ks)*64+lane)*8+j, hi frags[0], lo frags[12288].
// set1 (w_ih) / set2 (w_hh): 12 col-tiles x 2 k-chunks at (2+2*set)*12288.

__global__ __launch_bounds__(256) void wprep_kernel(
    const float* __restrict__ W, const float* __restrict__ w_ih,
    const float* __restrict__ w_hh, unsigned short* __restrict__ frags) {
  int idx = blockIdx.x * 256 + threadIdx.x;
  if (idx < 1536) {
    int lane = idx & 63;
    int ks = (idx >> 6) % 6;
    int tci = idx / (6 * 64);
    int c = tci * 16 + (lane & 15);
    size_t dbase = ((size_t)(tci * 6 + ks) * 64 + lane) * 8;
#pragma unroll
    for (int j = 0; j < 8; ++j) {
      int k = ks * 32 + ((lane >> 4) << 3) + j;  // 0..191
      int r = k >> 6, d = k & 63;
      float v = W[(r << 12) + (d << 6) + c];
      unsigned short h, l;
      split2(v, &h, &l);
      frags[dbase + j] = h;
      frags[12288 + dbase + j] = l;
    }
  } else if (idx < 1536 + 2 * 1536) {
    int i2 = idx - 1536;
    int set = i2 / 1536;
    int i3 = i2 % 1536;
    int lane = i3 & 63;
    int ks = (i3 >> 6) & 1;
    int tci = (i3 >> 7) % 12;
    int c = tci * 16 + (lane & 15);
    unsigned short* hi = frags + (size_t)(2 + 2 * set) * 12288;
    unsigned short* lo = hi + 12288;
    size_t dbase = ((size_t)(tci * 2 + ks) * 64 + lane) * 8;
    const float* wsrc = set ? w_hh : w_ih;
#pragma unroll
    for (int j = 0; j < 8; ++j) {
      int k = ks * 32 + ((lane >> 4) << 3) + j;
      float v = wsrc[(c << 6) + k];
      unsigned short h, l;
      split2(v, &h, &l);
      hi[dbase + j] = h;
      lo[dbase + j] = l;
    }
  }
}

// ---------------- CSR build ----------------

__global__ __launch_bounds__(256) void count_kernel(
    const int* __restrict__ dst, unsigned* __restrict__ counts, int E) {
  int base = (blockIdx.x * 256 + threadIdx.x) * 4;
  if (base + 4 <= E) {
    int4 d = *(const int4*)(dst + base);
    atomicAdd(&counts[d.x], 1u);
    atomicAdd(&counts[d.y], 1u);
    atomicAdd(&counts[d.z], 1u);
    atomicAdd(&counts[d.w], 1u);
  } else {
    for (int k = base; k < E; ++k) atomicAdd(&counts[dst[k]], 1u);
  }
}

__global__ __launch_bounds__(1024) void scan_k1(
    const unsigned* __restrict__ counts, unsigned* __restrict__ offs,
    unsigned* __restrict__ bsums, int N) {
  __shared__ unsigned sm[1024];
  int tid = threadIdx.x;
  int i = blockIdx.x * 1024 + tid;
  unsigned v = (i < N) ? counts[i] : 0u;
  sm[tid] = v;
  __syncthreads();
  for (int ofs = 1; ofs < 1024; ofs <<= 1) {
    unsigned add = (tid >= ofs) ? sm[tid - ofs] : 0u;
    __syncthreads();
    sm[tid] += add;
    __syncthreads();
  }
  if (i < N) offs[i] = sm[tid] - v;
  if (tid == 0) bsums[blockIdx.x] = sm[1023];
}

__global__ __launch_bounds__(128) void scan_k2(
    unsigned* __restrict__ bsums, unsigned* __restrict__ offs, int M, int N) {
  __shared__ unsigned sm[128];
  int tid = threadIdx.x;
  unsigned v = (tid < M) ? bsums[tid] : 0u;
  sm[tid] = v;
  __syncthreads();
  for (int ofs = 1; ofs < 128; ofs <<= 1) {
    unsigned add = (tid >= ofs) ? sm[tid - ofs] : 0u;
    __syncthreads();
    sm[tid] += add;
    __syncthreads();
  }
  if (tid < M) bsums[tid] = sm[tid] - v;
  if (tid == 127) offs[N] = sm[127];
}

__global__ __launch_bounds__(256) void scan_k3(
    unsigned* __restrict__ offs, const unsigned* __restrict__ bsums, int N) {
  int i = blockIdx.x * 256 + threadIdx.x;
  if (i < N) offs[i] = offs[i] + bsums[i >> 10];
}

__global__ __launch_bounds__(128) void bin_init_kernel(
    const unsigned* __restrict__ offs, unsigned* __restrict__ bincur, int nbins) {
  int b = threadIdx.x;
  if (b < nbins) bincur[b] = offs[b << 10];
}

// pass 1: block-aggregated scatter into dst-bins.
#define SCHUNK 2048
__global__ __launch_bounds__(256) void bin_scatter_kernel(
    const int* __restrict__ src, const int* __restrict__ dst,
    const int* __restrict__ rel, const float* __restrict__ norm,
    unsigned* __restrict__ bincur, uint2* __restrict__ binbuf, int E) {
  __shared__ unsigned cnt[128];
  __shared__ unsigned base[128];
  int tid = threadIdx.x;
  int start = blockIdx.x * SCHUNK;
  if (tid < 128) cnt[tid] = 0u;
  __syncthreads();
  unsigned mybin[8];
  uint2 myrec[8];
#pragma unroll
  for (int i = 0; i < 8; ++i) {
    int e = start + i * 256 + tid;
    if (e < E) {
      int d = dst[e];
      mybin[i] = (unsigned)d >> 10;
      myrec[i].x = (unsigned)src[e] | ((unsigned)rel[e] << 17) |
                   ((unsigned)(d & 1023) << 19);
      myrec[i].y = __builtin_bit_cast(unsigned, norm[e]);
      atomicAdd(&cnt[mybin[i]], 1u);
    } else {
      mybin[i] = 0xFFFFFFFFu;
    }
  }
  __syncthreads();
  if (tid < 128) {
    unsigned c = cnt[tid];
    base[tid] = c ? atomicAdd(&bincur[tid], c) : 0u;
    cnt[tid] = 0u;
  }
  __syncthreads();
#pragma unroll
  for (int i = 0; i < 8; ++i) {
    if (mybin[i] != 0xFFFFFFFFu) {
      unsigned r = atomicAdd(&cnt[mybin[i]], 1u);
      binbuf[base[mybin[i]] + r] = myrec[i];
    }
  }
}

// pass 2: per-bin counting sort by (dst, rel); emits per-node run lengths rcnt.
__global__ __launch_bounds__(1024) void bin_sort_kernel(
    const uint2* __restrict__ binbuf, const unsigned* __restrict__ offs,
    uint2* __restrict__ epack, unsigned* __restrict__ rcnt, int N) {
  __shared__ unsigned cnt[3 * 1024];  // per (rel, dlo) counts -> cursors
  __shared__ unsigned offl[1024];
  int bin = blockIdx.x;
  int base = bin << 10;
  int tid = threadIdx.x;
  int hi = base + 1024;
  if (hi > N) hi = N;
  if (base + tid < N) offl[tid] = offs[base + tid];
  cnt[tid] = 0u;
  cnt[1024 + tid] = 0u;
  cnt[2048 + tid] = 0u;
  __syncthreads();
  unsigned start = offs[base];
  unsigned end = offs[hi];
  for (unsigned j = start + tid; j < end; j += 1024) {
    uint2 rec = binbuf[j];
    unsigned dlo = rec.x >> 19;
    unsigned r = (rec.x >> 17) & 3;
    atomicAdd(&cnt[r * 1024 + dlo], 1u);
  }
  __syncthreads();
  unsigned c0 = cnt[tid], c1 = cnt[1024 + tid];
  int n = base + tid;
  if (n < N) rcnt[n] = c0 | (c1 << 16);
  unsigned o = (n < N) ? offl[tid] : 0u;
  cnt[tid] = o;
  cnt[1024 + tid] = o + c0;
  cnt[2048 + tid] = o + c0 + c1;
  __syncthreads();
  for (unsigned j = start + tid; j < end; j += 1024) {
    uint2 rec = binbuf[j];
    unsigned dlo = rec.x >> 19;
    unsigned r = (rec.x >> 17) & 3;
    unsigned p = atomicAdd(&cnt[r * 1024 + dlo], 1u);
    epack[p] = rec;
  }
}

// ---------------- fused layer: gather + Wcat-GEMM + GRU ----------------
// Per block: 16 nodes. Phase 1 gathers z[3][64] (rel-sorted runs, fp32).
// Phase 2: K=192 split-bf16 MFMA -> swh tile (LDS). Phase 3: GRU MFMAs +
// register gates; LAYER=0 writes fp32 h1, LAYER=1 reads hf rows for the
// h-path (split in-kernel) and hp (exact fp32), writes fp32 out.

template <int LAYER>
__global__ __launch_bounds__(256) void layer_kernel(
    const float* __restrict__ xf, const unsigned* __restrict__ offs,
    const unsigned* __restrict__ rcnt, const uint2* __restrict__ epack,
    const unsigned short* __restrict__ wft,
    const unsigned short* __restrict__ wfi, const unsigned short* __restrict__ wfh,
    const float* __restrict__ b_ih, const float* __restrict__ b_hh,
    float* __restrict__ outf, int N) {
  __shared__ float zld[16][197];
  __shared__ float swht[16][69];
  int tid = threadIdx.x;
  int n0 = blockIdx.x << 4;

  // ---- phase 1: gather (one 16-lane group per node; rel runs) ----
  {
    int g = tid >> 4, l16 = tid & 15;
    int n = n0 + g;
    int c4 = l16 << 2;
    float z0[4] = {}, z1[4] = {}, z2[4] = {};
    if (n < N) {
      unsigned a = offs[n], b = offs[n + 1];
      unsigned rc = rcnt[n];
      unsigned b1 = a + (rc & 0xFFFFu), b2 = b1 + (rc >> 16);
      auto run = [&](unsigned s, unsigned e, float* z) {
        unsigned j = s;
        for (; j + 2 <= e; j += 2) {
          uint2 e0 = epack[j], e1 = epack[j + 1];
          float4 v0 = *(const float4*)(xf + (((size_t)(e0.x & 0x1FFFFu)) << 6) + c4);
          float4 v1 = *(const float4*)(xf + (((size_t)(e1.x & 0x1FFFFu)) << 6) + c4);
          float nv0 = __builtin_bit_cast(float, e0.y);
          float nv1 = __builtin_bit_cast(float, e1.y);
          z[0] = fmaf(nv0, v0.x, fmaf(nv1, v1.x, z[0]));
          z[1] = fmaf(nv0, v0.y, fmaf(nv1, v1.y, z[1]));
          z[2] = fmaf(nv0, v0.z, fmaf(nv1, v1.z, z[2]));
          z[3] = fmaf(nv0, v0.w, fmaf(nv1, v1.w, z[3]));
        }
        if (j < e) {
          uint2 e0 = epack[j];
          float4 v0 = *(const float4*)(xf + (((size_t)(e0.x & 0x1FFFFu)) << 6) + c4);
          float nv0 = __builtin_bit_cast(float, e0.y);
          z[0] = fmaf(nv0, v0.x, z[0]);
          z[1] = fmaf(nv0, v0.y, z[1]);
          z[2] = fmaf(nv0, v0.z, z[2]);
          z[3] = fmaf(nv0, v0.w, z[3]);
        }
      };
      run(a, b1, z0);
      run(b1, b2, z1);
      run(b2, b, z2);
    }
#pragma unroll
    for (int i = 0; i < 4; ++i) {
      zld[g][c4 + i] = z0[i];
      zld[g][64 + c4 + i] = z1[i];
      zld[g][128 + c4 + i] = z2[i];
    }
  }
  __syncthreads();

  // ---- phase 2: z @ Wcat (K=192) -> swht ----
  int lane = tid & 63, w = tid >> 6;
  int r15 = lane & 15, kq = lane >> 4;
  {
    const short8* fh = (const short8*)wft;
    const short8* fl = (const short8*)(wft + 12288);
    f32x4 acc = {0.f, 0.f, 0.f, 0.f};
#pragma unroll
    for (int ks = 0; ks < 6; ++ks) {
      const float* zr = &zld[r15][ks * 32 + (kq << 3)];
      short8 th, tl;
#pragma unroll
      for (int jj = 0; jj < 8; ++jj) {
        unsigned short h_, l_;
        split2(zr[jj], &h_, &l_);
        th[jj] = (short)h_;
        tl[jj] = (short)l_;
      }
      bf16x8 ahi = __builtin_bit_cast(bf16x8, th);
      bf16x8 alo = __builtin_bit_cast(bf16x8, tl);
      bf16x8 bhi = __builtin_bit_cast(bf16x8, fh[(w * 6 + ks) * 64 + lane]);
      bf16x8 blo = __builtin_bit_cast(bf16x8, fl[(w * 6 + ks) * 64 + lane]);
      acc = MFMA16(ahi, bhi, acc);
      acc = MFMA16(ahi, blo, acc);
      acc = MFMA16(alo, bhi, acc);
    }
    int c = (w << 4) + r15;
#pragma unroll
    for (int reg = 0; reg < 4; ++reg) swht[(kq << 2) + reg][c] = acc[reg];
  }
  __syncthreads();

  // ---- phase 3: GRU ----
  {
    int c = (w << 4) + r15;
    int row = n0 + r15;
    if (row >= N) row = N - 1;

    bf16x8 axh[2], axl[2], ahh2[2], ahl2[2];
#pragma unroll
    for (int ks = 0; ks < 2; ++ks) {
      const float* sr = &swht[r15][ks * 32 + (kq << 3)];
      short8 th, tl;
#pragma unroll
      for (int jj = 0; jj < 8; ++jj) {
        unsigned short h_, l_;
        split2(sr[jj], &h_, &l_);
        th[jj] = (short)h_;
        tl[jj] = (short)l_;
      }
      axh[ks] = __builtin_bit_cast(bf16x8, th);
      axl[ks] = __builtin_bit_cast(bf16x8, tl);
    }
    if (LAYER) {
#pragma unroll
      for (int ks = 0; ks < 2; ++ks) {
        const float* hr = xf + (((size_t)row) << 6) + ks * 32 + (kq << 3);
        float4 h0 = *(const float4*)hr;
        float4 h1v = *(const float4*)(hr + 4);
        float hv[8] = {h0.x, h0.y, h0.z, h0.w, h1v.x, h1v.y, h1v.z, h1v.w};
        short8 th, tl;
#pragma unroll
        for (int jj = 0; jj < 8; ++jj) {
          unsigned short h_, l_;
          split2(hv[jj], &h_, &l_);
          th[jj] = (short)h_;
          tl[jj] = (short)l_;
        }
        ahh2[ks] = __builtin_bit_cast(bf16x8, th);
        ahl2[ks] = __builtin_bit_cast(bf16x8, tl);
      }
    }

    const short8* fih = (const short8*)wfi;
    const short8* fil = (const short8*)(wfi + 12288);
    const short8* fhh = (const short8*)wfh;
    const short8* fhl = (const short8*)(wfh + 12288);
    f32x4 accx[3], acch[3];
#pragma unroll
    for (int g = 0; g < 3; ++g) {
      accx[g] = (f32x4){0.f, 0.f, 0.f, 0.f};
      acch[g] = (f32x4){0.f, 0.f, 0.f, 0.f};
#pragma unroll
      for (int ks = 0; ks < 2; ++ks) {
        int tci = (g << 2) + w;
        bf16x8 bih = __builtin_bit_cast(bf16x8, fih[(tci * 2 + ks) * 64 + lane]);
        bf16x8 bil = __builtin_bit_cast(bf16x8, fil[(tci * 2 + ks) * 64 + lane]);
        accx[g] = MFMA16(axh[ks], bih, accx[g]);
        accx[g] = MFMA16(axh[ks], bil, accx[g]);
        accx[g] = MFMA16(axl[ks], bih, accx[g]);
        if (LAYER) {
          bf16x8 bhh = __builtin_bit_cast(bf16x8, fhh[(tci * 2 + ks) * 64 + lane]);
          bf16x8 bhl = __builtin_bit_cast(bf16x8, fhl[(tci * 2 + ks) * 64 + lane]);
          acch[g] = MFMA16(ahh2[ks], bhh, acch[g]);
          acch[g] = MFMA16(ahh2[ks], bhl, acch[g]);
          acch[g] = MFMA16(ahl2[ks], bhh, acch[g]);
        }
      }
    }

    float bi0 = b_ih[c], bi1 = b_ih[64 + c], bi2 = b_ih[128 + c];
    float bh0 = b_hh[c], bh1 = b_hh[64 + c], bh2 = b_hh[128 + c];
#pragma unroll
    for (int reg = 0; reg < 4; ++reg) {
      int n = n0 + (kq << 2) + reg;
      if (n >= N) break;
      size_t idx = (((size_t)n) << 6) + c;
      float hp = LAYER ? xf[idx] : 0.f;
      float gir = accx[0][reg] + bi0;
      float giz = accx[1][reg] + bi1;
      float gin = accx[2][reg] + bi2;
      float ghr = (LAYER ? acch[0][reg] : 0.f) + bh0;
      float ghz = (LAYER ? acch[1][reg] : 0.f) + bh1;
      float ghn = (LAYER ? acch[2][reg] : 0.f) + bh2;
      float r = fast_rcp(1.f + __expf(-(gir + ghr)));
      float z = fast_rcp(1.f + __expf(-(giz + ghz)));
      float nn = 1.f - 2.f * fast_rcp(1.f + __expf(2.f * (gin + r * ghn)));
      outf[idx] = (1.f - z) * nn + z * hp;
    }
  }
}

// ---------------- batchnorm ----------------

__global__ __launch_bounds__(256) void bn_stats_kernel(
    const float* __restrict__ h, float* __restrict__ stats, int N) {
  int tid = threadIdx.x;
  int c = tid & 63;
  float s = 0.f, ss = 0.f;
  for (int n = blockIdx.x * 4 + (tid >> 6); n < N; n += gridDim.x * 4) {
    float v = h[(size_t)n * 64 + c];
    s += v;
    ss += v * v;
  }
  __shared__ float sm[2][256];
  sm[0][tid] = s;
  sm[1][tid] = ss;
  __syncthreads();
  if (tid < 64) {
    s = sm[0][tid] + sm[0][tid + 64] + sm[0][tid + 128] + sm[0][tid + 192];
    ss = sm[1][tid] + sm[1][tid + 64] + sm[1][tid + 128] + sm[1][tid + 192];
    atomicAdd(&stats[tid], s);
    atomicAdd(&stats[64 + tid], ss);
  }
}

__global__ __launch_bounds__(256) void bn_apply_kernel(
    float* out, const float* __restrict__ stats,
    const float* __restrict__ gamma, const float* __restrict__ beta,
    int N, int total) {
  int idx = blockIdx.x * 256 + threadIdx.x;
  if (idx >= total) return;
  int c = idx & 63;
  float invN = 1.f / (float)N;
  float mean = stats[c] * invN;
  float var = stats[64 + c] * invN - mean * mean;
  float sc = rsqrtf(var + 1e-5f) * gamma[c];
  float sh = beta[c] - mean * sc;
  out[idx] = out[idx] * sc + sh;
}

// ---------------- launch ----------------

extern "C" void kernel_launch(void* const* d_in, const int* in_sizes, int n_in,
                              void* d_out, int out_size, void* d_ws, size_t ws_size,
                              hipStream_t stream) {
  const float* h     = (const float*)d_in[0];
  const float* norm  = (const float*)d_in[1];
  const float* W     = (const float*)d_in[2];
  const float* w_ih  = (const float*)d_in[3];
  const float* w_hh  = (const float*)d_in[4];
  const float* b_ih  = (const float*)d_in[5];
  const float* b_hh  = (const float*)d_in[6];
  const float* gamma = (const float*)d_in[7];
  const float* beta  = (const float*)d_in[8];
  const int* src     = (const int*)d_in[9];
  const int* dst     = (const int*)d_in[10];
  const int* rel     = (const int*)d_in[11];
  float* out = (float*)d_out;

  const int N = in_sizes[0] / 64;
  const int E = in_sizes[1];
  const int NT = (N + 15) / 16;
  const int NBINS = (N + 1023) / 1024;

  char* wsp = (char*)d_ws;
  float* hf = (float*)wsp;                      wsp += (size_t)N * 64 * 4;  // fp32 h1
  unsigned short* frags = (unsigned short*)wsp; wsp += 6 * 12288 * 2;
  unsigned* offs = (unsigned*)wsp;   wsp += ((size_t)N + 4) * 4;
  unsigned* cursor = (unsigned*)wsp; wsp += (size_t)N * 4;
  unsigned* rcnt = (unsigned*)wsp;   wsp += (size_t)N * 4;
  uint2* epack = (uint2*)wsp;        wsp += (size_t)E * 8;
  unsigned* bsums = (unsigned*)wsp;  wsp += 128 * 4;
  float* stats = (float*)wsp;        wsp += 128 * 4;

  uint2* binbuf = (uint2*)hf;  // aliases hf: dead until layer_kernel<0> writes it
  unsigned* bincur = cursor;   // reuse counter buffer (dead after scan)

  const unsigned short* frag_t = frags;
  const unsigned short* frag_i = frags + 2 * 12288;
  const unsigned short* frag_h = frags + 4 * 12288;

  const int M = (N + 1023) / 1024;

  hipMemsetAsync(cursor, 0, (size_t)N * 4, stream);
  hipMemsetAsync(stats, 0, 128 * 4, stream);

  wprep_kernel<<<18, 256, 0, stream>>>(W, w_ih, w_hh, frags);

  // CSR over dst (graph is layer-invariant): count -> scan -> (dst,rel) sort
  count_kernel<<<(E / 4 + 255) / 256, 256, 0, stream>>>(dst, cursor, E);
  scan_k1<<<M, 1024, 0, stream>>>(cursor, offs, bsums, N);
  scan_k2<<<1, 128, 0, stream>>>(bsums, offs, M, N);
  scan_k3<<<(N + 255) / 256, 256, 0, stream>>>(offs, bsums, N);
  bin_init_kernel<<<1, 128, 0, stream>>>(offs, bincur, NBINS);
  bin_scatter_kernel<<<(E + SCHUNK - 1) / SCHUNK, 256, 0, stream>>>(
      src, dst, rel, norm, bincur, binbuf, E);
  bin_sort_kernel<<<NBINS, 1024, 0, stream>>>(binbuf, offs, epack, rcnt, N);

  // layer 0: gather from input h; GRU (hstate=0) -> fp32 h1
  layer_kernel<0><<<NT, 256, 0, stream>>>(h, offs, rcnt, epack, frag_t,
                                          frag_i, frag_h, b_ih, b_hh, hf, N);
  // layer 1: gather from h1; GRU (h-path from h1) -> fp32 out
  layer_kernel<1><<<NT, 256, 0, stream>>>(hf, offs, rcnt, epack, frag_t,
                                          frag_i, frag_h, b_ih, b_hh, out, N);

  bn_stats_kernel<<<256, 256, 0, stream>>>(out, stats, N);
  int total = N * 64;
  bn_apply_kernel<<<(total + 255) / 256, 256, 0, stream>>>(out, stats, gamma,
                                                           beta, N, total);
}